// Round 1
// baseline (151.863 us; speedup 1.0000x reference)
//
#include <hip/hip_runtime.h>
#include <hip/hip_bf16.h>

typedef __bf16 bf16x8 __attribute__((ext_vector_type(8)));
typedef float  f32x4  __attribute__((ext_vector_type(4)));

#define MFMA16(a,b,c) __builtin_amdgcn_mfma_f32_16x16x32_bf16((a),(b),(c),0,0,0)

__device__ __forceinline__ unsigned short f2bf(float f){
  unsigned int u = __float_as_uint(f);
  u += 0x7fffu + ((u >> 16) & 1u);
  return (unsigned short)(u >> 16);
}

constexpr int BG = 128;
constexpr float SCALE_LOG2E = 0.125f * 1.4426950408889634f; // 1/sqrt(64) * log2(e)

// ---------------- prep kernels ----------------

__global__ void k_starts(const int* __restrict__ batch, int* __restrict__ starts, int total){
  const int t = threadIdx.x;
  if (t <= BG){
    int lo = 0, hi = total;
    while (lo < hi){ int mid = (lo + hi) >> 1; if (batch[mid] < t) lo = mid + 1; else hi = mid; }
    starts[t] = lo;
  }
}

// qs[q][f] = queries[q]·Wq[f] + bq[f]
__global__ void k_qs(const float* __restrict__ queries, const float* __restrict__ ipw,
                     const float* __restrict__ ipb, float* __restrict__ qs){
  __shared__ __align__(16) float qrow[256];
  const int t = threadIdx.x, q = blockIdx.x;
  qrow[t] = queries[q*256 + t];
  __syncthreads();
  const float* wr = ipw + (size_t)t*256;
  float acc = 0.f;
  #pragma unroll 8
  for (int j = 0; j < 256; j += 4){
    float4 wv = *reinterpret_cast<const float4*>(wr + j);
    float4 qv = *reinterpret_cast<const float4*>(&qrow[j]);
    acc += wv.x*qv.x + wv.y*qv.y + wv.z*qv.z + wv.w*qv.w;
  }
  qs[q*256 + t] = acc + ipb[t];
}

// Aq[m][f] = (scale*log2e) * sum_d qs[q][h*64+d] * Wk[h*64+d][f],  m = h*32+q
__global__ void k_aq(const float* __restrict__ qs, const float* __restrict__ ipw,
                     unsigned short* __restrict__ Aq){
  __shared__ float ql[64];
  const int t = threadIdx.x, m = blockIdx.x;
  const int h = m >> 5, q = m & 31;
  if (t < 64) ql[t] = qs[q*256 + h*64 + t];
  __syncthreads();
  const float* wk = ipw + (size_t)(256 + h*64)*256 + t;
  float acc = 0.f;
  #pragma unroll 8
  for (int d = 0; d < 64; d++) acc += ql[d] * wk[(size_t)d*256];
  Aq[m*256 + t] = f2bf(acc * SCALE_LOG2E);
}

// Cmat_t[g][h*256+f] = sum_d Wv[h*64+d][f] * Wo[g][h*64+d];  cvec[g] = bv·Wo[g] + bo[g]
__global__ void k_cmat(const float* __restrict__ ipw, const float* __restrict__ opw,
                       const float* __restrict__ ipb, const float* __restrict__ opb,
                       unsigned short* __restrict__ Cmat, float* __restrict__ cvec){
  __shared__ float wo[256];
  __shared__ float red[256];
  const int t = threadIdx.x, g = blockIdx.x;
  wo[t] = opw[(size_t)g*256 + t];
  __syncthreads();
  #pragma unroll
  for (int h = 0; h < 4; h++){
    const float* wv = ipw + (size_t)(512 + h*64)*256 + t;
    float acc = 0.f;
    #pragma unroll 8
    for (int d = 0; d < 64; d++) acc += wv[(size_t)d*256] * wo[h*64 + d];
    Cmat[(size_t)g*1024 + h*256 + t] = f2bf(acc);
  }
  red[t] = ipb[512 + t] * wo[t];
  __syncthreads();
  for (int off = 128; off > 0; off >>= 1){
    if (t < off) red[t] += red[t + off];
    __syncthreads();
  }
  if (t == 0) cvec[g] = red[0] + opb[g];
}

// ---------------- fused flash attention over raw x ----------------
// grid 256 = graph*2 splits, 512 threads (8 waves, wave = (head, q-half): 16 rows)

__device__ __forceinline__ void load_chunk(float4 stg[4], const float* __restrict__ x,
                                           int nstart, int cnt, int c, int tid){
  const int c0 = c*32;
  #pragma unroll
  for (int k = 0; k < 4; k++){
    const int idx = tid + (k << 9);
    const int node = idx & 31, dq = idx >> 5;
    const int nl = c0 + node;
    float4 v = make_float4(0.f, 0.f, 0.f, 0.f);
    if (nl < cnt) v = *reinterpret_cast<const float4*>(x + (size_t)(nstart + nl)*256 + dq*4);
    stg[k] = v;
  }
}

__global__ __launch_bounds__(512, 2) void k_attn(
    const float* __restrict__ x, const int* __restrict__ starts,
    const unsigned short* __restrict__ Aq,
    float* __restrict__ partO, float* __restrict__ partM, float* __restrict__ partL)
{
  __shared__ __align__(16) unsigned short xsub[32*264];  // [node][dim], padded (S reads)
  __shared__ __align__(16) unsigned short xT  [256*40];  // [dim][node], padded (PV reads)
  __shared__ __align__(16) unsigned short Plds[128*40];  // 8 waves x [16 rows][node]

  const int tid = threadIdx.x;
  const int wave = tid >> 6, lane = tid & 63, lg = lane >> 4, li = lane & 15;
  const int bid = blockIdx.x;
  const int g = bid >> 1, s = bid & 1;
  const int s0 = starts[g], s1 = starts[g+1];
  const int cntg = s1 - s0;
  const int half = (cntg + 1) >> 1;
  const int nstart = s0 + s*half;
  int cnt = cntg - s*half; cnt = cnt < 0 ? 0 : (cnt > half ? half : cnt);
  const int chunks = (cnt + 31) >> 5;

  const int wavebase = (wave >> 1)*32 + (wave & 1)*16;  // first (h,q) row of this wave

  // Aq fragments for this wave's 16 rows (A operand, rows=lane&15, 8 contiguous k per lane)
  bf16x8 afrag[8];
  {
    const unsigned short* ap = Aq + (size_t)(wavebase + li)*256 + lg*8;
    #pragma unroll
    for (int kb = 0; kb < 8; kb++)
      afrag[kb] = *reinterpret_cast<const bf16x8*>(ap + kb*32);
  }

  f32x4 oacc[16];
  #pragma unroll
  for (int i = 0; i < 16; i++) oacc[i] = f32x4{0.f,0.f,0.f,0.f};
  float rmax[4], rsum[4];
  #pragma unroll
  for (int r = 0; r < 4; r++){ rmax[r] = -1e30f; rsum[r] = 0.f; }

  float4 stg[4];
  if (chunks > 0) load_chunk(stg, x, nstart, cnt, 0, tid);

  for (int c = 0; c < chunks; c++){
    __syncthreads();   // previous compute done reading LDS
    // stage registers -> LDS (both layouts), convert to bf16
    #pragma unroll
    for (int k = 0; k < 4; k++){
      const int idx = tid + (k << 9);
      const int node = idx & 31, dq = idx >> 5;
      const unsigned short b0 = f2bf(stg[k].x), b1 = f2bf(stg[k].y);
      const unsigned short b2 = f2bf(stg[k].z), b3 = f2bf(stg[k].w);
      *reinterpret_cast<ushort4*>(&xsub[node*264 + dq*4]) = make_ushort4(b0,b1,b2,b3);
      const int d0 = dq*4;
      xT[(d0+0)*40 + node] = b0;
      xT[(d0+1)*40 + node] = b1;
      xT[(d0+2)*40 + node] = b2;
      xT[(d0+3)*40 + node] = b3;
    }
    __syncthreads();
    if (c + 1 < chunks) load_chunk(stg, x, nstart, cnt, c + 1, tid);  // overlap with compute

    const int c0 = c*32;
    // ---- S = Aq @ x^T  (rows = wave's 16 (h,q) rows, cols = 32 nodes) ----
    f32x4 sacc[2];
    sacc[0] = f32x4{0.f,0.f,0.f,0.f}; sacc[1] = f32x4{0.f,0.f,0.f,0.f};
    #pragma unroll
    for (int kb = 0; kb < 8; kb++){
      #pragma unroll
      for (int ni = 0; ni < 2; ni++){
        const bf16x8 b = *reinterpret_cast<const bf16x8*>(&xsub[(ni*16 + li)*264 + kb*32 + lg*8]);
        sacc[ni] = MFMA16(afrag[kb], b, sacc[ni]);
      }
    }
    // mask invalid nodes
    #pragma unroll
    for (int ni = 0; ni < 2; ni++){
      if (c0 + ni*16 + li >= cnt){
        sacc[ni][0] = -1e30f; sacc[ni][1] = -1e30f; sacc[ni][2] = -1e30f; sacc[ni][3] = -1e30f;
      }
    }
    // ---- online softmax (exp2 domain; log2e folded into Aq) ----
    float al[4];
    #pragma unroll
    for (int r = 0; r < 4; r++){
      float cm = fmaxf(sacc[0][r], sacc[1][r]);
      cm = fmaxf(cm, __shfl_xor(cm, 1));
      cm = fmaxf(cm, __shfl_xor(cm, 2));
      cm = fmaxf(cm, __shfl_xor(cm, 4));
      cm = fmaxf(cm, __shfl_xor(cm, 8));
      const float nm = fmaxf(rmax[r], cm);
      al[r] = __builtin_exp2f(rmax[r] - nm);
      rmax[r] = nm;
      rsum[r] *= al[r];
      #pragma unroll
      for (int ni = 0; ni < 2; ni++){
        const float p = __builtin_exp2f(sacc[ni][r] - nm);
        rsum[r] += p;   // per-lane partial over its columns; reduced at the end
        Plds[(wave*16 + lg*4 + r)*40 + ni*16 + li] = f2bf(p);
      }
    }
    #pragma unroll
    for (int fi = 0; fi < 16; fi++){
      #pragma unroll
      for (int r = 0; r < 4; r++) oacc[fi][r] *= al[r];
    }
    // ---- PV: O += P(16x32) @ x(32x256) ----
    const bf16x8 pa = *reinterpret_cast<const bf16x8*>(&Plds[(wave*16 + li)*40 + lg*8]);
    #pragma unroll
    for (int fi = 0; fi < 16; fi++){
      const bf16x8 b = *reinterpret_cast<const bf16x8*>(&xT[(fi*16 + li)*40 + lg*8]);
      oacc[fi] = MFMA16(pa, b, oacc[fi]);
    }
  }

  // reduce row sums across the 16 column-lanes
  #pragma unroll
  for (int r = 0; r < 4; r++){
    float t = rsum[r];
    t += __shfl_xor(t, 1); t += __shfl_xor(t, 2); t += __shfl_xor(t, 4); t += __shfl_xor(t, 8);
    rsum[r] = t;
  }
  const int pbase = bid*128;
  #pragma unroll
  for (int r = 0; r < 4; r++){
    const int row = wavebase + lg*4 + r;
    #pragma unroll
    for (int fi = 0; fi < 16; fi++)
      partO[(size_t)(pbase + row)*256 + fi*16 + li] = oacc[fi][r];
    if (li == 0){ partM[pbase + row] = rmax[r]; partL[pbase + row] = rsum[r]; }
  }
}

// ---------------- combine partials + out-proj GEMM ----------------
// grid 256 = (graph, q-half); out[g*32+q][:] = Pn[q][:1024] @ Cmat_t^T + cvec

__global__ __launch_bounds__(512, 1) void k_out(
    const float* __restrict__ partO, const float* __restrict__ partM, const float* __restrict__ partL,
    const unsigned short* __restrict__ Cmat, const float* __restrict__ cvec,
    float* __restrict__ out)
{
  __shared__ __align__(16) unsigned short plds[16*1024];  // [q'][(h,f)] XOR-swizzled
  __shared__ float s0s[64], s1s[64];
  const int tid = threadIdx.x;
  const int g = blockIdx.x >> 1, qh = blockIdx.x & 1;
  const int p0 = 2*g, p1 = 2*g + 1;
  if (tid < 64){
    const int h = tid >> 4, qr = tid & 15;
    const int row = h*32 + qh*16 + qr;
    const float m0 = partM[p0*128 + row], m1 = partM[p1*128 + row];
    const float M  = fmaxf(m0, m1);
    const float e0 = __builtin_exp2f(m0 - M), e1 = __builtin_exp2f(m1 - M);
    const float L  = e0*partL[p0*128 + row] + e1*partL[p1*128 + row];
    const float inv = 1.f / L;
    s0s[tid] = e0*inv; s1s[tid] = e1*inv;
  }
  __syncthreads();
  #pragma unroll
  for (int i = 0; i < 32; i++){
    const int idx = tid + i*512;
    const int col = idx & 1023, qr = idx >> 10;
    const int h = col >> 8, f = col & 255;
    const int row = h*32 + qh*16 + qr;
    const float v = s0s[h*16 + qr]*partO[(size_t)(p0*128 + row)*256 + f]
                  + s1s[h*16 + qr]*partO[(size_t)(p1*128 + row)*256 + f];
    const int bc = (col*2) ^ ((qr & 7) << 4);
    *reinterpret_cast<unsigned short*>(reinterpret_cast<char*>(plds) + qr*2048 + bc) = f2bf(v);
  }
  __syncthreads();
  const int wave = tid >> 6, lane = tid & 63, lg = lane >> 4, li = lane & 15;
  f32x4 acc0 = {0.f,0.f,0.f,0.f}, acc1 = {0.f,0.f,0.f,0.f};
  const float cv0 = cvec[wave*32 + li], cv1 = cvec[wave*32 + 16 + li];
  const unsigned short* cb0 = Cmat + (size_t)(wave*32 + li)*1024;
  const unsigned short* cb1 = Cmat + (size_t)(wave*32 + 16 + li)*1024;
  #pragma unroll 8
  for (int kb = 0; kb < 32; kb++){
    const int bc = ((kb*32 + lg*8)*2) ^ ((li & 7) << 4);
    const bf16x8 a  = *reinterpret_cast<const bf16x8*>(reinterpret_cast<const char*>(plds) + li*2048 + bc);
    const bf16x8 b0 = *reinterpret_cast<const bf16x8*>(cb0 + kb*32 + lg*8);
    const bf16x8 b1 = *reinterpret_cast<const bf16x8*>(cb1 + kb*32 + lg*8);
    acc0 = MFMA16(a, b0, acc0);
    acc1 = MFMA16(a, b1, acc1);
  }
  #pragma unroll
  for (int r = 0; r < 4; r++){
    const int q = lg*4 + r;
    const size_t orow = (size_t)(g*32 + qh*16 + q)*256;
    out[orow + wave*32 + li]      = acc0[r] + cv0;
    out[orow + wave*32 + 16 + li] = acc1[r] + cv1;
  }
}

// ---------------- launch ----------------

extern "C" void kernel_launch(void* const* d_in, const int* in_sizes, int n_in,
                              void* d_out, int out_size, void* d_ws, size_t ws_size,
                              hipStream_t stream)
{
  const float* x       = (const float*)d_in[0];
  const int*   batch   = (const int*)d_in[1];
  const float* queries = (const float*)d_in[2];
  const float* ipw     = (const float*)d_in[3];
  const float* ipb     = (const float*)d_in[4];
  const float* opw     = (const float*)d_in[5];
  const float* opb     = (const float*)d_in[6];
  float* out = (float*)d_out;
  const int total = in_sizes[1];

  char* w = (char*)d_ws;
  int*            starts = (int*)(w);
  float*          qs     = (float*)(w + 1024);
  unsigned short* Aq     = (unsigned short*)(w + 36*1024);
  unsigned short* Cmat   = (unsigned short*)(w + 102*1024);
  float*          cvec   = (float*)(w + 616*1024);
  float*          partO  = (float*)(w + (size_t)1024*1024);
  float*          partM  = (float*)(w + (size_t)1024*1024 + (size_t)256*128*256*4);
  float*          partL  = (float*)(w + (size_t)1024*1024 + (size_t)256*128*256*4 + 131072);

  k_starts<<<1, 256, 0, stream>>>(batch, starts, total);
  k_qs<<<32, 256, 0, stream>>>(queries, ipw, ipb, qs);
  k_aq<<<128, 256, 0, stream>>>(qs, ipw, Aq);
  k_cmat<<<256, 256, 0, stream>>>(ipw, opw, ipb, opb, Cmat, cvec);
  k_attn<<<256, 512, 0, stream>>>(x, starts, Aq, partO, partM, partL);
  k_out<<<256, 512, 0, stream>>>(partO, partM, partL, Cmat, cvec, out);
}